// Round 19
// baseline (82.896 us; speedup 1.0000x reference)
//
#include <hip/hip_runtime.h>
#include <hip/hip_bf16.h>

#define S_ 1024
#define D_ 128
#define V_ 100000
#define VSTRIPS_ 3136   // 32-row v-strips; 3125 valid (=100000), 11 zero pads
#define NPHASE_ 64      // 64 phases x 49 strips = 3136
#define N_ 4096
#define PADROWS_ 352.0f

typedef __attribute__((ext_vector_type(4))) float f32x4;
typedef __attribute__((ext_vector_type(4))) int   i32x4;
typedef __attribute__((ext_vector_type(8))) int   i32x8;

#define LOG2E_ 1.4426950408889634f
#define LN2_64_ 0.010830424696225f   // ln2 / 64 (fp4 scale 2^-3 on each operand)

__device__ __forceinline__ float exp2_fast(float x) {
#if __has_builtin(__builtin_amdgcn_exp2f)
    return __builtin_amdgcn_exp2f(x);
#else
    return exp2f(x);
#endif
}

// e2m1 round-to-nearest in the x8 domain: grid {0,.5,1,1.5,2,3,4,6}
__device__ __forceinline__ unsigned int fp4q(float t) {
    float a = fabsf(t);
    unsigned int c;
    if      (a < 0.25f) c = 0;
    else if (a < 0.75f) c = 1;
    else if (a < 1.25f) c = 2;
    else if (a < 1.75f) c = 3;
    else if (a < 2.50f) c = 4;
    else if (a < 3.50f) c = 5;
    else if (a < 5.00f) c = 6;
    else                c = 7;
    return (t < 0.f && c) ? (c | 8u) : c;
}

__device__ __forceinline__ float fp4dec(int c) {
    int m = c & 1, e = (c >> 1) & 3;
    float v = (e == 0) ? 0.5f * (float)m
                       : (1.0f + 0.5f * (float)m) * (float)(1 << (e - 1));
    return (c & 8) ? -v : v;
}

// ---- kernel 1: prep = knorm (fragment-major fp4 Kn) + qnorm (row-major fp4 Qn) ----
// Kn strip = 2KB (32 rows x 128 k, e2m1, x8 domain, scale 2^-3 applied by MFMA).
// B element (r local, k): lane = (r&15)+16*(k>>5), byte (k&31)>>1, nibble k&1
//   -> addr = (r>>4)*1024 + ((r&15)+16*(k>>5))*16 + ((k&31)>>1)
// B-operand read (nn-half): addr = nn*1024 + lane*16 + [0..15] (one i32x4).
__global__ void prep_kernel(const float* __restrict__ K, const float* __restrict__ Q,
                            const int* __restrict__ loc,
                            char* __restrict__ Kn, char* __restrict__ Qn,
                            float* __restrict__ Ssum) {
    __shared__ char sm[2048];
    const int bid = blockIdx.x;
    const int tid = threadIdx.x;
    const int lane = tid & 63;
    const int wvv = tid >> 6;
    if (bid < VSTRIPS_) {                      // ---- K strip ----
        char* dst = Kn + (size_t)bid * 2048;
        if (bid >= 3125) {                     // zero pad strip: fp4 0x0 = 0.0
            if (tid < 128)
                *(f32x4*)(dst + tid * 16) = (f32x4){0.f, 0.f, 0.f, 0.f};
            return;
        }
        #pragma unroll
        for (int i = 0; i < 8; ++i) {
            int r = wvv * 8 + i;
            float2 v = ((const float2*)(K + ((size_t)bid * 32 + r) * D_))[lane];
            float ss = v.x * v.x + v.y * v.y;
            #pragma unroll
            for (int off = 32; off; off >>= 1) ss += __shfl_xor(ss, off);
            float rn8 = rsqrtf(ss) * 8.0f;     // x8 domain for e2m1
            // k = 2*lane (lo nibble), 2*lane+1 (hi nibble); byte = lane&15
            unsigned int byte = fp4q(v.x * rn8) | (fp4q(v.y * rn8) << 4);
            int addr = ((r >> 4) << 10) + (((r & 15) + ((lane >> 4) << 4)) << 4)
                     + (lane & 15);
            *(unsigned char*)(sm + addr) = (unsigned char)byte;
        }
        __syncthreads();
        if (tid < 128)
            *(f32x4*)(dst + tid * 16) = *(const f32x4*)(sm + tid * 16);
    } else {                                   // ---- Q rows (4 per block) ----
        int w = (bid - VSTRIPS_) * 4 + wvv;
        if (lane == 0) Ssum[w] = 0.f;
        int b = loc[2 * w], s = loc[2 * w + 1];
        float2 v = ((const float2*)(Q + ((size_t)b * S_ + (size_t)s) * D_))[lane];
        float ss = v.x * v.x + v.y * v.y;
        #pragma unroll
        for (int off = 32; off; off >>= 1) ss += __shfl_xor(ss, off);
        float rn8 = rsqrtf(ss) * LOG2E_ * 8.0f;   // exp2 domain, x8 for e2m1
        unsigned int byte = fp4q(v.x * rn8) | (fp4q(v.y * rn8) << 4);
        *(unsigned char*)(Qn + (size_t)w * 64 + lane) = (unsigned char)byte;
    }
}

// ---- kernel 2: main  sum_v exp2(q . k_v)  -- fp4 K=128, NO LDS, NO BARRIERS ----
// mfma_scale_f32_16x16x128_f8f6f4 with cbsz=blgp=4 (e2m1), scales 124 = 2^-3
// each -> acc = exp2-domain logits. fp4 data lives in the LOW 4 VGPRs of each
// 8-reg operand (loads write them in place; high half unused by HW).
// Wave: 64q x 32v (m=4, nn=2 -> 8 MFMA + 32 exp2 per strip).
__global__ __launch_bounds__(256, 1) void ce_main(
    const char* __restrict__ Qn,
    const char* __restrict__ Kn,
    float* __restrict__ Ssum)
{
    const int tid  = threadIdx.x;
    const int lane = tid & 63;
    const int wv   = tid >> 6;
    const int r0   = lane & 15;
    const int hi   = lane >> 4;          // 0..3

    // grid (16,64): XCD owns 8 whole phase-groups (all 16 q-blocks of each)
    const int fid   = blockIdx.y * 16 + blockIdx.x;
    const int xcd   = fid & 7;
    const int idx   = fid >> 3;              // 0..127
    const int phase = xcd * 8 + (idx >> 4);  // 0..63
    const int qb    = idx & 15;              // 0..15 (256 q-rows each)

    // ---- Q fragments (fp4) -> low half of i32x8 regs ----
    // A-lane l: row = l&15, k = (l>>4)*32+[0..31] -> bytes row*64 + hi*16 + [0..15]
    i32x8 afr[4];
    {
        const char* qsrc = Qn + ((size_t)qb * 256 + wv * 64 + r0) * 64 + (hi << 4);
        #pragma unroll
        for (int m = 0; m < 4; ++m) {
            afr[m] = (i32x8){0, 0, 0, 0, 0, 0, 0, 0};
            *(i32x4*)&afr[m] = *(const i32x4*)(qsrc + m * 1024);
        }
    }

    // strip j (0..48) at phase + NPHASE_*j; operand = base + lane*16 (+1024 nn=1)
    const char* kvbase = Kn + (size_t)phase * 2048 + (lane << 4);

#define LOADSET(B0, B1, j) do {                                              \
        const char* p = kvbase + (size_t)(j) * (2048 * NPHASE_);             \
        *(i32x4*)&B0 = *(const i32x4*)(p);                                   \
        *(i32x4*)&B1 = *(const i32x4*)(p + 1024);                            \
    } while (0)

#define COMPUTE(B0, B1, ACC) do {                                            \
        _Pragma("unroll")                                                    \
        for (int m = 0; m < 4; ++m) {                                        \
            ACC[m][0] = __builtin_amdgcn_mfma_scale_f32_16x16x128_f8f6f4(    \
                afr[m], B0, fz, 4, 4, 0, 124, 0, 124);                       \
            ACC[m][1] = __builtin_amdgcn_mfma_scale_f32_16x16x128_f8f6f4(    \
                afr[m], B1, fz, 4, 4, 0, 124, 0, 124);                       \
        }                                                                    \
    } while (0)

#define EXP2S(ACC) do {                                                      \
        _Pragma("unroll")                                                    \
        for (int m = 0; m < 4; ++m)                                          \
            _Pragma("unroll")                                                \
            for (int q = 0; q < 4; ++q)                                      \
                psum[m][q] += exp2_fast(ACC[m][0][q]) + exp2_fast(ACC[m][1][q]); \
    } while (0)

    float psum[4][4];
    #pragma unroll
    for (int m = 0; m < 4; ++m)
        #pragma unroll
        for (int q = 0; q < 4; ++q) psum[m][q] = 0.f;

    const f32x4 fz = {0.f, 0.f, 0.f, 0.f};
    f32x4 accE[4][2], accO[4][2];
    #pragma unroll
    for (int m = 0; m < 4; ++m)
        #pragma unroll
        for (int nn = 0; nn < 2; ++nn)
            accO[m][nn] = (f32x4){-16384.f, -16384.f, -16384.f, -16384.f}; // exp2 -> 0

    i32x8 RA0 = {0,0,0,0,0,0,0,0}, RA1 = RA0, RB0 = RA0, RB1 = RA0;
    LOADSET(RA0, RA1, 0);
    #pragma unroll 1
    for (int j = 0; j < 48; j += 2) {
        LOADSET(RB0, RB1, j + 1);        // prefetch next strip
        EXP2S(accO);                     // strip j-1 exp2 under load latency
        COMPUTE(RA0, RA1, accE);         // strip j
        LOADSET(RA0, RA1, j + 2);        // j+2 <= 48: valid
        EXP2S(accE);                     // strip j
        COMPUTE(RB0, RB1, accO);         // strip j+1
    }
    // epilogue: strip 48 (already in RA)
    EXP2S(accO);                         // strip 47
    COMPUTE(RA0, RA1, accE);             // strip 48
    EXP2S(accE);                         // strip 48

#undef LOADSET
#undef COMPUTE
#undef EXP2S

    // C/D 16x16: col=lane&15 (v), row=hi*4+reg (q). Reduce over v-cols, atomics.
    #pragma unroll
    for (int m = 0; m < 4; ++m) {
        #pragma unroll
        for (int q = 0; q < 4; ++q) {
            float v = psum[m][q];
            v += __shfl_xor(v, 1);
            v += __shfl_xor(v, 2);
            v += __shfl_xor(v, 4);
            v += __shfl_xor(v, 8);
            if (r0 == 0) {
                int row = qb * 256 + wv * 64 + m * 16 + hi * 4 + q;
                atomicAdd(&Ssum[row], v);
            }
        }
    }
}

// ---- kernel 3: per-row term = log(S - PADROWS) - true_logit ----
// fp4 decode both sides; logit = sum(qval*kval) / 64, exp2-domain (log2e in Q).
__global__ void term_kernel(const char* __restrict__ Qn,
                            const char* __restrict__ Kn,
                            const int* __restrict__ labels,
                            const float* __restrict__ Ssum,
                            float* __restrict__ T) {
    int w = (blockIdx.x * blockDim.x + threadIdx.x) >> 6;
    int lane = threadIdx.x & 63;
    if (w >= N_) return;
    int lab = labels[w];
    int qc = *(const unsigned char*)(Qn + (size_t)w * 64 + lane);
    int r = lab & 31;
    int kc = *(const unsigned char*)(Kn + ((size_t)(lab >> 5)) * 2048
                 + ((r >> 4) << 10) + (((r & 15) + ((lane >> 4) << 4)) << 4)
                 + (lane & 15));
    float d = fp4dec(qc & 15) * fp4dec(kc & 15)
            + fp4dec(qc >> 4) * fp4dec(kc >> 4);
    #pragma unroll
    for (int off = 32; off; off >>= 1) d += __shfl_xor(d, off);
    if (lane == 0) T[w] = logf(Ssum[w] - PADROWS_) - d * LN2_64_;
}

// ---- kernel 4: mean over N ----
__global__ void reduce_kernel(const float* __restrict__ T, float* __restrict__ out) {
    __shared__ float sm[4];
    float s = 0.f;
    for (int i = threadIdx.x; i < N_; i += 256) s += T[i];
    #pragma unroll
    for (int off = 32; off; off >>= 1) s += __shfl_xor(s, off);
    if ((threadIdx.x & 63) == 0) sm[threadIdx.x >> 6] = s;
    __syncthreads();
    if (threadIdx.x == 0) out[0] = (sm[0] + sm[1] + sm[2] + sm[3]) * (1.0f / (float)N_);
}

extern "C" void kernel_launch(void* const* d_in, const int* in_sizes, int n_in,
                              void* d_out, int out_size, void* d_ws, size_t ws_size,
                              hipStream_t stream) {
    (void)in_sizes; (void)n_in; (void)out_size; (void)ws_size;
    const float* Q   = (const float*)d_in[0];
    const float* K   = (const float*)d_in[1];
    const int* loc   = (const int*)d_in[2];
    const int* labels= (const int*)d_in[3];
    float* out = (float*)d_out;

    char* ws = (char*)d_ws;
    char* Kn    = ws;                                   // 3136*2048 = 6,422,528 B
    char* Qn    = ws + 6422528;                         // N_*64     =   262,144 B
    float* Ssum = (float*)(ws + 6422528 + 262144);      // N_*4
    float* T    = Ssum + N_;                            // N_*4

    prep_kernel<<<VSTRIPS_ + N_ / 4, 256, 0, stream>>>(K, Q, loc, Kn, Qn, Ssum);
    ce_main<<<dim3(16, NPHASE_), 256, 0, stream>>>(Qn, Kn, Ssum);
    term_kernel<<<N_ / 4, 256, 0, stream>>>(Qn, Kn, labels, Ssum, T);
    reduce_kernel<<<1, 256, 0, stream>>>(T, out);
}